// Round 1
// 1411.665 us; speedup vs baseline: 2.2499x; 2.2499x over previous
//
#include <hip/hip_runtime.h>
#include <hip/hip_bf16.h>

#define LNUM 128
#define NNODES 30000
#define NEDGES 150000
#define NSTEPS 5

// NOTE (r17 discovery): d_out is FLOAT32 (reference is pure jnp.float32).
// NOTE (this round): block_edge/block_node moved to MFMA via split-f16
// (x = hi + lo/2048, lo scaled to avoid f16 denormal flush in MFMA).
// 3 MFMAs per frag pair, 2 f32 accs -> ~f32 accuracy at matrix-core rate.

typedef _Float16 f16;
typedef __attribute__((ext_vector_type(8))) _Float16 f16x8;
typedef __attribute__((ext_vector_type(4))) float f32x4;

// ---------------------------------------------------------------------------
// Legacy VALU MLP core: still used by the (small) encoder kernels.
// ---------------------------------------------------------------------------
template<int ROWS, int K, int KP>
__device__ __forceinline__ void mlp_apply(
    const float* __restrict__ xs, float* __restrict__ hv,
    float* __restrict__ mu_s, float* __restrict__ rs_s,
    const float* __restrict__ W1, const float* __restrict__ b1,
    const float* __restrict__ W2, const float* __restrict__ b2,
    const float* __restrict__ g,  const float* __restrict__ be,
    float out[ROWS])
{
    const int t = threadIdx.x;
    float acc[ROWS];
    {
        const float bb = b1[t];
        #pragma unroll
        for (int r = 0; r < ROWS; r++) acc[r] = bb;
    }
    int k = 0;
    for (; k + 4 <= K; k += 4) {
        const float w0 = W1[(k + 0) * LNUM + t];
        const float w1 = W1[(k + 1) * LNUM + t];
        const float w2 = W1[(k + 2) * LNUM + t];
        const float w3 = W1[(k + 3) * LNUM + t];
        #pragma unroll
        for (int r = 0; r < ROWS; r++) {
            const float4 x = *(const float4*)(xs + r * KP + k);
            acc[r] = fmaf(x.x, w0, acc[r]);
            acc[r] = fmaf(x.y, w1, acc[r]);
            acc[r] = fmaf(x.z, w2, acc[r]);
            acc[r] = fmaf(x.w, w3, acc[r]);
        }
    }
    for (; k < K; ++k) {
        const float w = W1[k * LNUM + t];
        #pragma unroll
        for (int r = 0; r < ROWS; r++) acc[r] = fmaf(xs[r * KP + k], w, acc[r]);
    }
    #pragma unroll
    for (int r = 0; r < ROWS; r++) hv[r * LNUM + t] = fmaxf(acc[r], 0.f);
    __syncthreads();
    {
        const float bb = b2[t];
        #pragma unroll
        for (int r = 0; r < ROWS; r++) acc[r] = bb;
    }
    for (int k2 = 0; k2 < LNUM; k2 += 4) {
        const float w0 = W2[(k2 + 0) * LNUM + t];
        const float w1 = W2[(k2 + 1) * LNUM + t];
        const float w2 = W2[(k2 + 2) * LNUM + t];
        const float w3 = W2[(k2 + 3) * LNUM + t];
        #pragma unroll
        for (int r = 0; r < ROWS; r++) {
            const float4 x = *(const float4*)(hv + r * LNUM + k2);
            acc[r] = fmaf(x.x, w0, acc[r]);
            acc[r] = fmaf(x.y, w1, acc[r]);
            acc[r] = fmaf(x.z, w2, acc[r]);
            acc[r] = fmaf(x.w, w3, acc[r]);
        }
    }
    __syncthreads();
    #pragma unroll
    for (int r = 0; r < ROWS; r++) hv[r * LNUM + t] = fmaxf(acc[r], 0.f);
    __syncthreads();
    if (t < ROWS) {
        float s = 0.f, s2 = 0.f;
        for (int kk = 0; kk < LNUM; kk++) {
            const float v = hv[t * LNUM + kk];
            s += v; s2 += v * v;
        }
        const float m = s * (1.0f / LNUM);
        mu_s[t] = m;
        rs_s[t] = rsqrtf(fmaxf(s2 * (1.0f / LNUM) - m * m, 0.f) + 1e-5f);
    }
    __syncthreads();
    const float gg = g[t], bbe = be[t];
    #pragma unroll
    for (int r = 0; r < ROWS; r++)
        out[r] = fmaf(gg * (hv[r * LNUM + t] - mu_s[r]), rs_s[r], bbe);
}

__global__ __launch_bounds__(128) void encode_nodes_k(
    const float* __restrict__ u, const float* __restrict__ load_,
    const float* __restrict__ ntype,
    const float* __restrict__ W1, const float* __restrict__ b1,
    const float* __restrict__ W2, const float* __restrict__ b2,
    const float* __restrict__ g,  const float* __restrict__ be,
    float* __restrict__ nl)
{
    constexpr int ROWS = 4, K = 12, KP = 12;
    __shared__ __align__(16) float xs[ROWS * KP];
    __shared__ __align__(16) float hv[ROWS * LNUM];
    __shared__ float mu_s[ROWS], rs_s[ROWS];
    const int t = threadIdx.x;
    const int base = blockIdx.x * ROWS;
    if (t < ROWS * K) {
        const int r = t / K, k = t % K;
        const int n = base + r;
        float v;
        if (k < 2)      v = u[n * 2 + k];
        else if (k < 3) v = load_[n];
        else            v = ntype[n * 9 + (k - 3)];
        xs[r * KP + k] = v;
    }
    __syncthreads();
    float out[ROWS];
    mlp_apply<ROWS, K, KP>(xs, hv, mu_s, rs_s, W1, b1, W2, b2, g, be, out);
    #pragma unroll
    for (int r = 0; r < ROWS; r++) nl[(base + r) * LNUM + t] = out[r];
}

__global__ __launch_bounds__(128) void encode_edges_k(
    const float* __restrict__ mesh_pos, const float* __restrict__ u,
    const int* __restrict__ senders, const int* __restrict__ receivers,
    const float* __restrict__ W1, const float* __restrict__ b1,
    const float* __restrict__ W2, const float* __restrict__ b2,
    const float* __restrict__ g,  const float* __restrict__ be,
    float* __restrict__ el)
{
    constexpr int ROWS = 4, K = 5, KP = 8;
    __shared__ __align__(16) float xs[ROWS * KP];
    __shared__ __align__(16) float hv[ROWS * LNUM];
    __shared__ float mu_s[ROWS], rs_s[ROWS];
    const int t = threadIdx.x;
    const int base = blockIdx.x * ROWS;
    if (t < ROWS) {
        const int e = base + t;
        const int s = senders[e], rcv = receivers[e];
        const float rx = mesh_pos[s * 2 + 0] - mesh_pos[rcv * 2 + 0];
        const float ry = mesh_pos[s * 2 + 1] - mesh_pos[rcv * 2 + 1];
        const float d  = sqrtf(rx * rx + ry * ry);
        const float g0 = u[s * 2 + 0] - u[rcv * 2 + 0];
        const float g1 = u[s * 2 + 1] - u[rcv * 2 + 1];
        float* row = xs + t * KP;
        row[0] = rx; row[1] = ry; row[2] = d; row[3] = g0; row[4] = g1;
        row[5] = 0.f; row[6] = 0.f; row[7] = 0.f;
    }
    __syncthreads();
    float out[ROWS];
    mlp_apply<ROWS, K, KP>(xs, hv, mu_s, rs_s, W1, b1, W2, b2, g, be, out);
    #pragma unroll
    for (int r = 0; r < ROWS; r++) el[(size_t)(base + r) * LNUM + t] = out[r];
}

// ---------------------------------------------------------------------------
// Weight prep: f32 [S][K][128] -> f16 hi/lo tables transposed to [S][128][K].
// lo is scaled by 2048 so it stays in f16 normal range.
// ---------------------------------------------------------------------------
#define PE1 245760   // 5*384*128 (edge W1)
#define PE2 81920    // 5*128*128 (edge W2)
#define PN1 163840   // 5*256*128 (node W1)
#define PN2 81920    // 5*128*128 (node W2)

__global__ __launch_bounds__(256) void prep_w_all_k(
    const float* __restrict__ eW1, const float* __restrict__ eW2,
    const float* __restrict__ nW1, const float* __restrict__ nW2,
    f16* __restrict__ out)
{
    int i = blockIdx.x * 256 + threadIdx.x;
    const float* W; f16 *hi, *lo; int K; int j = i;
    if (j < PE1)                    { W = eW1; K = 384; hi = out;                         lo = hi + PE1; }
    else if ((j -= PE1) < PE2)      { W = eW2; K = 128; hi = out + 2*PE1;                 lo = hi + PE2; }
    else if ((j -= PE2) < PN1)      { W = nW1; K = 256; hi = out + 2*PE1 + 2*PE2;         lo = hi + PN1; }
    else if ((j -= PN1) < PN2)      { W = nW2; K = 128; hi = out + 2*PE1 + 2*PE2 + 2*PN1; lo = hi + PN2; }
    else return;
    const int k = j % K;
    const int rem = j / K;
    const int n = rem & 127;
    const int s = rem >> 7;
    const float v = W[((size_t)s * K + k) * 128 + n];
    const f16 h = (f16)v;
    hi[j] = h;
    lo[j] = (f16)((v - (float)h) * 2048.f);
}

// ---------------------------------------------------------------------------
// MFMA GraphNet block MLP. 256 threads = 4 waves, 64-row tile, N=128 out.
// Wave w owns rows [w*16, w*16+16): LN is a 16-lane shuffle reduction.
// A/B staged per 32-wide K chunk in padded LDS (stride 40 f16 -> ~2-way
// bank aliasing, free). Layer-1 output re-split into wave-private Y rows.
// ---------------------------------------------------------------------------
template<int K1, bool EDGE>
__global__ __launch_bounds__(256) void mlp_block_k(
    const float* __restrict__ nl_in,   // EDGE: node latents (read). NODE: unused.
    float* __restrict__ io,            // EDGE: el (RMW). NODE: nl (RMW).
    float* __restrict__ aggr,          // EDGE: atomic dst. NODE: read.
    const int* __restrict__ senders, const int* __restrict__ receivers,
    const f16* __restrict__ W1h, const f16* __restrict__ W1l, const float* __restrict__ b1,
    const f16* __restrict__ W2h, const f16* __restrict__ W2l, const float* __restrict__ b2,
    const float* __restrict__ gam, const float* __restrict__ bet)
{
    constexpr int NCH1 = K1 / 32;
    constexpr int ROWMAX = EDGE ? NEDGES : NNODES;

    __shared__ __align__(16) f16 Ah[64][40];
    __shared__ __align__(16) f16 Al[64][40];
    __shared__ __align__(16) f16 Bh[128][40];
    __shared__ __align__(16) f16 Bl[128][40];
    __shared__ __align__(16) f16 Yh[64][136];
    __shared__ __align__(16) f16 Yl[64][136];
    __shared__ int sidx[64], ridx[64];

    const int t = threadIdx.x;
    const int base = blockIdx.x * 64;

    if constexpr (EDGE) {
        if (t < 64) {
            const int e = min(base + t, NEDGES - 1);
            sidx[t] = senders[e];
            ridx[t] = receivers[e];
        }
    }
    __syncthreads();

    const int w  = t >> 6;
    const int l  = t & 63;
    const int lr = l & 15;   // M/N index within fragment
    const int lg = l >> 4;   // k-group
    const int sr = t >> 2;         // staging row 0..63
    const int sc = (t & 3) * 8;    // staging col offset 0,8,16,24

    const f32x4 zero4 = {0.f, 0.f, 0.f, 0.f};
    f32x4 accH[8], accL[8];
    #pragma unroll
    for (int nf = 0; nf < 8; nf++) { accH[nf] = zero4; accL[nf] = zero4; }

    // ---------------- layer 1: [64,K1] @ [K1,128] ----------------
    for (int kc = 0; kc < NCH1; ++kc) {
        __syncthreads();
        {   // stage A chunk (gather + split)
            const int col = kc * 32 + sc;
            const float* src;
            if constexpr (EDGE) {
                if (col < 128)      src = nl_in + (size_t)sidx[sr] * 128 + col;
                else if (col < 256) src = nl_in + (size_t)ridx[sr] * 128 + (col - 128);
                else                src = io + (size_t)min(base + sr, NEDGES - 1) * 128 + (col - 256);
            } else {
                const int n = min(base + sr, NNODES - 1);
                if (col < 128) src = io   + (size_t)n * 128 + col;
                else           src = aggr + (size_t)n * 128 + (col - 128);
            }
            const float4 x0 = *(const float4*)src;
            const float4 x1 = *(const float4*)(src + 4);
            const float xv[8] = {x0.x, x0.y, x0.z, x0.w, x1.x, x1.y, x1.z, x1.w};
            union { f16 h[8]; uint4 u; } ph, pl;
            #pragma unroll
            for (int j = 0; j < 8; j++) {
                const f16 h = (f16)xv[j];
                ph.h[j] = h;
                pl.h[j] = (f16)((xv[j] - (float)h) * 2048.f);
            }
            *(uint4*)(&Ah[sr][sc]) = ph.u;
            *(uint4*)(&Al[sr][sc]) = pl.u;
        }
        {   // stage B chunk (prepped f16 weights, [n][k] layout)
            const int sel = t >> 7, n = t & 127;
            const f16* srcW = (sel ? W1l : W1h) + (size_t)n * K1 + kc * 32;
            f16* dst = sel ? &Bl[n][0] : &Bh[n][0];
            #pragma unroll
            for (int j2 = 0; j2 < 4; j2++)
                *(uint4*)(dst + j2 * 8) = *(const uint4*)(srcW + j2 * 8);
        }
        __syncthreads();
        const f16x8 ah = *(const f16x8*)(&Ah[w * 16 + lr][lg * 8]);
        const f16x8 al = *(const f16x8*)(&Al[w * 16 + lr][lg * 8]);
        #pragma unroll
        for (int nf = 0; nf < 8; nf++) {
            const f16x8 bh = *(const f16x8*)(&Bh[nf * 16 + lr][lg * 8]);
            const f16x8 bl = *(const f16x8*)(&Bl[nf * 16 + lr][lg * 8]);
            accH[nf] = __builtin_amdgcn_mfma_f32_16x16x32_f16(ah, bh, accH[nf], 0, 0, 0);
            accL[nf] = __builtin_amdgcn_mfma_f32_16x16x32_f16(ah, bl, accL[nf], 0, 0, 0);
            accL[nf] = __builtin_amdgcn_mfma_f32_16x16x32_f16(al, bh, accL[nf], 0, 0, 0);
        }
    }

    // layer-1 epilogue: bias + relu + split -> Y (wave-private rows, no barrier)
    #pragma unroll
    for (int nf = 0; nf < 8; nf++) {
        const float bb = b1[nf * 16 + lr];
        #pragma unroll
        for (int reg = 0; reg < 4; reg++) {
            float v = accH[nf][reg] + accL[nf][reg] * (1.f / 2048.f) + bb;
            v = fmaxf(v, 0.f);
            const f16 h = (f16)v;
            const int row = w * 16 + lg * 4 + reg;   // D layout: row=(l>>4)*4+reg
            Yh[row][nf * 16 + lr] = h;               //           col=l&15
            Yl[row][nf * 16 + lr] = (f16)((v - (float)h) * 2048.f);
        }
        accH[nf] = zero4; accL[nf] = zero4;
    }

    // ---------------- layer 2: [64,128] @ [128,128] ----------------
    for (int kc = 0; kc < 4; ++kc) {
        __syncthreads();
        {
            const int sel = t >> 7, n = t & 127;
            const f16* srcW = (sel ? W2l : W2h) + (size_t)n * 128 + kc * 32;
            f16* dst = sel ? &Bl[n][0] : &Bh[n][0];
            #pragma unroll
            for (int j2 = 0; j2 < 4; j2++)
                *(uint4*)(dst + j2 * 8) = *(const uint4*)(srcW + j2 * 8);
        }
        __syncthreads();
        const f16x8 ah = *(const f16x8*)(&Yh[w * 16 + lr][kc * 32 + lg * 8]);
        const f16x8 al = *(const f16x8*)(&Yl[w * 16 + lr][kc * 32 + lg * 8]);
        #pragma unroll
        for (int nf = 0; nf < 8; nf++) {
            const f16x8 bh = *(const f16x8*)(&Bh[nf * 16 + lr][lg * 8]);
            const f16x8 bl = *(const f16x8*)(&Bl[nf * 16 + lr][lg * 8]);
            accH[nf] = __builtin_amdgcn_mfma_f32_16x16x32_f16(ah, bh, accH[nf], 0, 0, 0);
            accL[nf] = __builtin_amdgcn_mfma_f32_16x16x32_f16(ah, bl, accL[nf], 0, 0, 0);
            accL[nf] = __builtin_amdgcn_mfma_f32_16x16x32_f16(al, bh, accL[nf], 0, 0, 0);
        }
    }

    // epilogue 2: bias + relu + LayerNorm + residual / scatter
    float vv[8][4];
    float s1[4] = {0, 0, 0, 0}, s2[4] = {0, 0, 0, 0};
    #pragma unroll
    for (int nf = 0; nf < 8; nf++) {
        const float bb = b2[nf * 16 + lr];
        #pragma unroll
        for (int reg = 0; reg < 4; reg++) {
            float v = accH[nf][reg] + accL[nf][reg] * (1.f / 2048.f) + bb;
            v = fmaxf(v, 0.f);
            vv[nf][reg] = v;
            s1[reg] += v;
            s2[reg] += v * v;
        }
    }
    #pragma unroll
    for (int m = 1; m < 16; m <<= 1) {
        #pragma unroll
        for (int reg = 0; reg < 4; reg++) {
            s1[reg] += __shfl_xor(s1[reg], m);
            s2[reg] += __shfl_xor(s2[reg], m);
        }
    }
    float gg[8], bb8[8];
    #pragma unroll
    for (int nf = 0; nf < 8; nf++) { gg[nf] = gam[nf * 16 + lr]; bb8[nf] = bet[nf * 16 + lr]; }

    #pragma unroll
    for (int reg = 0; reg < 4; reg++) {
        const float mu = s1[reg] * (1.f / 128.f);
        const float rs = rsqrtf(fmaxf(s2[reg] * (1.f / 128.f) - mu * mu, 0.f) + 1e-5f);
        const int row = w * 16 + lg * 4 + reg;
        const int idx = base + row;
        if (idx < ROWMAX) {
            if constexpr (EDGE) {
                const int rv = ridx[row];
                #pragma unroll
                for (int nf = 0; nf < 8; nf++) {
                    const int col = nf * 16 + lr;
                    const float ne = gg[nf] * (vv[nf][reg] - mu) * rs + bb8[nf];
                    atomicAdd(&aggr[(size_t)rv * 128 + col], ne);   // segment_sum
                    io[(size_t)idx * 128 + col] += ne;              // el residual
                }
            } else {
                #pragma unroll
                for (int nf = 0; nf < 8; nf++) {
                    const int col = nf * 16 + lr;
                    const float ne = gg[nf] * (vv[nf][reg] - mu) * rs + bb8[nf];
                    io[(size_t)idx * 128 + col] += ne;              // nl residual
                }
            }
        }
    }
}

// Decoder -> FLOAT32 output, layout [TW, N, TD].
__global__ __launch_bounds__(128) void decode_k(
    const float* __restrict__ nl,
    const float* __restrict__ W1, const float* __restrict__ b1,
    const float* __restrict__ W2, const float* __restrict__ b2,
    float* __restrict__ out)
{
    constexpr int NPB = 16;
    __shared__ __align__(16) float xs[NPB * LNUM];
    __shared__ float hh[NPB * 8];
    const int t = threadIdx.x;
    const int base = blockIdx.x * NPB;
    for (int r = 0; r < NPB; r++) xs[r * LNUM + t] = nl[(base + r) * LNUM + t];
    __syncthreads();
    {
        const int node = t >> 3, j = t & 7;       // 16 nodes x 8 hidden
        float a = b1[j];
        for (int k = 0; k < LNUM; k++) a = fmaf(xs[node * LNUM + k], W1[k * 8 + j], a);
        hh[node * 8 + j] = a / (1.f + expf(-a));  // Swish
    }
    __syncthreads();
    for (int idx = t; idx < NPB * 10; idx += 128) {
        const int node = idx / 10, c = idx % 10;
        float a = b2[c];
        #pragma unroll
        for (int j = 0; j < 8; j++) a = fmaf(hh[node * 8 + j], W2[j * 10 + c], a);
        const int tt = c >> 1, d = c & 1;
        out[(size_t)tt * (NNODES * 2) + (size_t)(base + node) * 2 + d] =
            a * (float)(tt + 1);
    }
}

__global__ __launch_bounds__(256) void zero_k(float* __restrict__ p, int n)
{
    const int i = blockIdx.x * 256 + threadIdx.x;
    if (i < n) p[i] = 0.f;
}

// ---------------------------------------------------------------------------
extern "C" void kernel_launch(void* const* d_in, const int* in_sizes, int n_in,
                              void* d_out, int out_size, void* d_ws, size_t ws_size,
                              hipStream_t stream) {
    const float* F[34];
    for (int i = 0; i < 34; i++) F[i] = (const float*)d_in[i];
    const int* senders   = (const int*)d_in[4];
    const int* receivers = (const int*)d_in[5];

    const size_t nN = (size_t)NNODES * LNUM;
    const size_t nE = (size_t)NEDGES * LNUM;
    float* nl   = (float*)d_ws;
    float* el   = nl + nN;
    float* aggr = el + nE;
    // prepped split-f16 weight tables (2.3 MB) after the f32 tensors
    f16* wbase = (f16*)(aggr + nN);
    f16* eW1h = wbase;
    f16* eW1l = eW1h + PE1;
    f16* eW2h = eW1l + PE1;
    f16* eW2l = eW2h + PE2;
    f16* nW1h = eW2l + PE2;
    f16* nW1l = nW1h + PN1;
    f16* nW2h = nW1l + PN1;
    f16* nW2l = nW2h + PN2;

    const int prep_total = PE1 + PE2 + PN1 + PN2;
    prep_w_all_k<<<(prep_total + 255) / 256, 256, 0, stream>>>(
        F[18], F[20], F[24], F[26], wbase);

    encode_nodes_k<<<NNODES / 4, 128, 0, stream>>>(
        F[2], F[3], F[1], F[6], F[7], F[8], F[9], F[10], F[11], nl);
    encode_edges_k<<<NEDGES / 4, 128, 0, stream>>>(
        F[0], F[2], senders, receivers,
        F[12], F[13], F[14], F[15], F[16], F[17], el);

    const int egrid = (NEDGES + 63) / 64;   // 2344
    const int ngrid = (NNODES + 63) / 64;   // 469

    for (int s = 0; s < NSTEPS; s++) {
        zero_k<<<(NNODES * LNUM + 255) / 256, 256, 0, stream>>>(aggr, NNODES * LNUM);
        mlp_block_k<3 * LNUM, true><<<egrid, 256, 0, stream>>>(
            nl, el, aggr, senders, receivers,
            eW1h + (size_t)s * 128 * 384, eW1l + (size_t)s * 128 * 384, F[19] + s * LNUM,
            eW2h + (size_t)s * 128 * 128, eW2l + (size_t)s * 128 * 128, F[21] + s * LNUM,
            F[22] + s * LNUM, F[23] + s * LNUM);
        mlp_block_k<2 * LNUM, false><<<ngrid, 256, 0, stream>>>(
            nullptr, nl, aggr, nullptr, nullptr,
            nW1h + (size_t)s * 128 * 256, nW1l + (size_t)s * 128 * 256, F[25] + s * LNUM,
            nW2h + (size_t)s * 128 * 128, nW2l + (size_t)s * 128 * 128, F[27] + s * LNUM,
            F[28] + s * LNUM, F[29] + s * LNUM);
    }

    decode_k<<<NNODES / 16, 128, 0, stream>>>(
        nl, F[30], F[31], F[32], F[33], (float*)d_out);
}